// Round 9
// baseline (106.982 us; speedup 1.0000x reference)
//
#include <hip/hip_runtime.h>
#include <hip/hip_bf16.h>

#define B_ 4
#define H_ 16
#define S_ 2048
#define D_ 64
#define BH_ (B_ * H_)
#define VSTR 2048  // compacted key stride (max padded length)

// log2-domain constant: Q pre-scale = 0.125 * log2(e)
#define QS 0.18033688011112042f

typedef __bf16 bf16_t;
typedef __attribute__((ext_vector_type(8))) bf16_t bf16x8;
typedef __attribute__((ext_vector_type(4))) bf16_t bf16x4;
typedef __attribute__((ext_vector_type(4))) float f32x4;

#if __has_builtin(__builtin_amdgcn_exp2f)
#define EX2(x) __builtin_amdgcn_exp2f(x)
#else
#define EX2(x) exp2f(x)
#endif

// ---- workspace layout (bytes) ----
#define KC_OFF 0u          // Kc  [bh][VSTR][64] bf16 = 16.8 MB
#define VT_OFF 16777216u   // Vtc [bh][64][VSTR] bf16 = 16.8 MB
#define CIDX_OFF 33554432u // cidx [B][2048] int
#define NK_OFF 33619968u   // nk [B] int

__device__ __forceinline__ bf16x4 cvt4(const float4 a) {
  return (bf16x4){(bf16_t)a.x, (bf16_t)a.y, (bf16_t)a.z, (bf16_t)a.w};
}

// ======================= scan: mask -> compact key indices =======================
// One block per b. Sniffs bool8 vs int32 (int32 0/1 has all bytes at off%4!=0 zero).
__global__ __launch_bounds__(256) void scan_kernel(const unsigned char* __restrict__ raw,
                                                   int* __restrict__ cidx,
                                                   int* __restrict__ nkarr) {
  const int b = blockIdx.x;
  const int tid = threadIdx.x;
  __shared__ int isBool;
  if (tid == 0) isBool = 0;
  __syncthreads();
  int any = 0;
  for (int i = tid; i < B_ * S_; i += 256)
    if ((i & 3) && raw[i]) any = 1;
  if (any) isBool = 1;  // benign race
  __syncthreads();
  const bool ib = (isBool != 0);

  int flags[8], cnt = 0;
  const int base = tid * 8;
#pragma unroll
  for (int j = 0; j < 8; ++j) {
    const int key = base + j;
    const int m = ib ? (raw[b * S_ + key] ? 1 : 0)
                     : (((const int*)raw)[b * S_ + key] ? 1 : 0);
    flags[j] = m ? 0 : 1;  // keep unmasked
    cnt += flags[j];
  }
  __shared__ int sc[256];
  sc[tid] = cnt;
  __syncthreads();
  for (int off = 1; off < 256; off <<= 1) {  // Hillis-Steele inclusive scan
    const int v = sc[tid];
    const int u = (tid >= off) ? sc[tid - off] : 0;
    __syncthreads();
    sc[tid] = v + u;
    __syncthreads();
  }
  int pos = (tid > 0) ? sc[tid - 1] : 0;  // exclusive
  const int total = sc[255];
  int* cb = cidx + b * VSTR;
#pragma unroll
  for (int j = 0; j < 8; ++j)
    if (flags[j]) cb[pos++] = base + j;
  if (tid == 0) nkarr[b] = total;
  const int padend = ((total + 63) >> 6) << 6;
  for (int i = total + tid; i < padend; i += 256) cb[i] = 0;  // pad -> key 0 (p gated to 0)
}

// ======================= gather: compact K (bf16) + V^T (bf16) =======================
__global__ __launch_bounds__(256) void gather_kernel(const float* __restrict__ K,
                                                     const float* __restrict__ V,
                                                     const int* __restrict__ cidx,
                                                     const int* __restrict__ nkarr,
                                                     bf16_t* __restrict__ Kc,
                                                     bf16_t* __restrict__ Vtc) {
  const int blk = blockIdx.x;  // bh*32 + tile
  const int bh = blk >> 5, tile = blk & 31;
  const int b = bh >> 4;
  if (tile * 64 >= nkarr[b]) return;
  const int tid = threadIdx.x;
  __shared__ int idx[64];
  __shared__ float T[64][65];
  if (tid < 64) idx[tid] = cidx[b * VSTR + tile * 64 + tid];
  __syncthreads();
  // K gather: 4 threads/row, 16 d each; rows are contiguous 256B reads.
  {
    const int row = tid >> 2, d0 = (tid & 3) << 4;
    const float* src = K + (size_t)bh * S_ * D_ + (size_t)idx[row] * D_ + d0;
    bf16_t* dst = Kc + (size_t)bh * VSTR * D_ + (size_t)(tile * 64 + row) * D_ + d0;
    const float4 a = ((const float4*)src)[0], bb = ((const float4*)src)[1];
    const float4 c = ((const float4*)src)[2], d = ((const float4*)src)[3];
    *(bf16x4*)(dst) = cvt4(a);
    *(bf16x4*)(dst + 4) = cvt4(bb);
    *(bf16x4*)(dst + 8) = cvt4(c);
    *(bf16x4*)(dst + 12) = cvt4(d);
  }
  // V gather + 64x64 transpose via LDS
  const float* vsrc = V + (size_t)bh * S_ * D_;
#pragma unroll
  for (int rep = 0; rep < 4; ++rep) {
    const int i2 = rep * 256 + tid;
    const int row = i2 >> 4, d4 = (i2 & 15) << 2;
    const float4 v = *(const float4*)(vsrc + (size_t)idx[row] * D_ + d4);
    T[row][d4] = v.x; T[row][d4 + 1] = v.y; T[row][d4 + 2] = v.z; T[row][d4 + 3] = v.w;
  }
  __syncthreads();
  bf16_t* vdst = Vtc + (size_t)bh * D_ * VSTR + tile * 64;
#pragma unroll
  for (int rep = 0; rep < 4; ++rep) {
    const int i2 = rep * 256 + tid;
    const int d = i2 >> 4, k4 = (i2 & 15) << 2;
    const bf16x4 o = {(bf16_t)T[k4][d], (bf16_t)T[k4 + 1][d], (bf16_t)T[k4 + 2][d],
                      (bf16_t)T[k4 + 3][d]};
    *(bf16x4*)(vdst + (size_t)d * VSTR + k4) = o;
  }
}

// ======================= main flash kernel =======================
// Block = one (b,h) x 256 Q-rows; 8 waves (512 thr) x 32 q (2 q-fragment
// chains). NEW vs R8: (1) 2-tile-deep global prefetch (register ping-pong,
// static via inlined lambda call sites) so Kc/Vtc HBM-miss latency (~900cyc;
// 33.6MB doesn't fit 4MB/XCD L2 alongside streaming Q) is fully hidden before
// the staged-LDS write; (2) l computed by ones-A-operand MFMA (every C row =
// sum_k P[k][q]) -> no per-tile ts adds, no epilogue shuffles.
// Compacted keys, log2 softmax (no max; scores bounded), pad-68 LDS
// (0 conflicts, measured), double-buffered, 1 barrier/tile, setprio on MFMA.

__device__ __forceinline__ bf16x8 pack8(const bf16x4 lo, const bf16x4 hi) {
  bf16x8 r;
  r[0] = lo[0]; r[1] = lo[1]; r[2] = lo[2]; r[3] = lo[3];
  r[4] = hi[0]; r[5] = hi[1]; r[6] = hi[2]; r[7] = hi[3];
  return r;
}

__device__ __forceinline__ bf16x8 qpack(const float4 a, const float4 b) {
  bf16x8 r;
  r[0] = (bf16_t)(a.x * QS); r[1] = (bf16_t)(a.y * QS);
  r[2] = (bf16_t)(a.z * QS); r[3] = (bf16_t)(a.w * QS);
  r[4] = (bf16_t)(b.x * QS); r[5] = (bf16_t)(b.y * QS);
  r[6] = (bf16_t)(b.z * QS); r[7] = (bf16_t)(b.w * QS);
  return r;
}

__global__ __launch_bounds__(512, 4) void attn_main_kernel(const float* __restrict__ Q,
                                                           const bf16_t* __restrict__ Kc,
                                                           const bf16_t* __restrict__ Vtc,
                                                           const int* __restrict__ nkarr,
                                                           float* __restrict__ out) {
  __shared__ bf16_t Kl[2][64][68];  // 136B rows: conflict-free (measured R1/R3/R7/R8)
  __shared__ bf16_t Vl[2][64][68];

  const int bid = blockIdx.x;
  const int wu = (bid & 7) * 64 + (bid >> 3);  // XCD swizzle, 512 = 8*64 bijective
  const int qt = wu & 7, bh = wu >> 3, b = bh >> 4;

  const int nk = nkarr[b];
  const int nt = (nk + 63) >> 6;

  const int tid = threadIdx.x, wid = tid >> 6, lane = tid & 63;
  const int g4 = ((lane >> 4) & 3) << 2, qi = lane & 15;

  const size_t bhoff = (size_t)bh * (S_ * D_);
  const bf16_t* Kg = Kc + (size_t)bh * VSTR * D_;
  const bf16_t* Vg = Vtc + (size_t)bh * D_ * VSTR;

  // 2 Q fragments (groups of 16 q), fp32 -> scaled bf16, held all kernel
  const int qrow0 = qt * 256 + wid * 32 + qi;
  bf16x8 qb[2][2];
#pragma unroll
  for (int g = 0; g < 2; ++g) {
    const float* qp = Q + bhoff + (size_t)(qrow0 + g * 16) * D_;
#pragma unroll
    for (int c = 0; c < 2; ++c)
      qb[g][c] = qpack(*(const float4*)(qp + c * 32 + g4),
                       *(const float4*)(qp + c * 32 + 16 + g4));
  }

  // all-ones A fragment for the l-MFMA (C[m][q] = sum_k P[k][q] in every row)
  bf16x8 ones;
#pragma unroll
  for (int j = 0; j < 8; ++j) ones[j] = (bf16_t)1.0f;

  // staging geometry: one row per thread (512 thr x 16B = one 64x64 bf16 tile)
  const int srow = tid >> 3;
  const int scol = (tid & 7) << 3;
  const bf16_t* Kgs = Kg + (size_t)srow * D_ + scol;   // + t*64*D_ per tile
  const bf16_t* Vgs = Vg + (size_t)srow * VSTR + scol; // + t*64  per tile

  // prologue: tile 0 -> LDS[0]; tile 1 -> regs (ping)
  {
    const uint4 k0 = *(const uint4*)(Kgs);
    const uint4 v0 = *(const uint4*)(Vgs);
    *(uint2*)&Kl[0][srow][scol] = make_uint2(k0.x, k0.y);
    *(uint2*)&Kl[0][srow][scol + 4] = make_uint2(k0.z, k0.w);
    *(uint2*)&Vl[0][srow][scol] = make_uint2(v0.x, v0.y);
    *(uint2*)&Vl[0][srow][scol + 4] = make_uint2(v0.z, v0.w);
  }
  uint4 kr0, vr0, kr1, vr1;
  if (nt > 1) {
    kr1 = *(const uint4*)(Kgs + (size_t)64 * D_);
    vr1 = *(const uint4*)(Vgs + 64);
  }
  __syncthreads();

  f32x4 o[2][4];
#pragma unroll
  for (int g = 0; g < 2; ++g)
#pragma unroll
    for (int dt = 0; dt < 4; ++dt) o[g][dt] = (f32x4){0.f, 0.f, 0.f, 0.f};
  f32x4 la[2] = {{0.f, 0.f, 0.f, 0.f}, {0.f, 0.f, 0.f, 0.f}};

  // step(t): compute tile t from LDS[t&1]; staged regs sk/sv hold tile t+1;
  // prefetch tile t+2 into pk/pv.
  auto step = [&](int t, uint4& sk, uint4& sv, uint4& pk, uint4& pv) {
    const int cur = t & 1, nxt = cur ^ 1;
    const int rem = nk - t * 64;  // < 64 only on the last tile

    // ---- issue prefetch for tile t+2 (consumed next iteration) ----
    if (t + 2 < nt) {
      pk = *(const uint4*)(Kgs + (size_t)(t + 2) * 64 * D_);
      pv = *(const uint4*)(Vgs + (t + 2) * 64);
    }

    // ---- QK^T with fused exp2 softmax (log2 domain, no max) ----
    bf16x8 pb0[2], pb1[2];
    __builtin_amdgcn_s_setprio(1);
#pragma unroll
    for (int kt = 0; kt < 4; ++kt) {
      f32x4 a0 = {0.f, 0.f, 0.f, 0.f}, a1 = a0;
#pragma unroll
      for (int c = 0; c < 2; ++c) {
        const bf16_t* kp = &Kl[cur][kt * 16 + qi][c * 32 + g4];
        const bf16x8 ka = pack8(*(const bf16x4*)kp, *(const bf16x4*)(kp + 16));
        a0 = __builtin_amdgcn_mfma_f32_16x16x32_bf16(ka, qb[0][c], a0, 0, 0, 0);
        a1 = __builtin_amdgcn_mfma_f32_16x16x32_bf16(ka, qb[1][c], a1, 0, 0, 0);
      }
      if (t + 1 < nt) {  // full tile: ungated exp2
#pragma unroll
        for (int r = 0; r < 4; ++r) {
          pb0[kt >> 1][(kt & 1) * 4 + r] = (bf16_t)EX2(a0[r]);
          pb1[kt >> 1][(kt & 1) * 4 + r] = (bf16_t)EX2(a1[r]);
        }
      } else {  // tail tile: gate pad slots (key >= nk)
#pragma unroll
        for (int r = 0; r < 4; ++r) {
          const int kidx = kt * 16 + g4 + r;
          float p0 = EX2(a0[r]);
          float p1 = EX2(a1[r]);
          p0 = (kidx < rem) ? p0 : 0.f;
          p1 = (kidx < rem) ? p1 : 0.f;
          pb0[kt >> 1][(kt & 1) * 4 + r] = (bf16_t)p0;
          pb1[kt >> 1][(kt & 1) * 4 + r] = (bf16_t)p1;
        }
      }
    }
    __builtin_amdgcn_s_setprio(0);

    // ---- write staged tile t+1 -> LDS[nxt] (loads issued >=1 full tile ago) ----
    if (t + 1 < nt) {
      *(uint2*)&Kl[nxt][srow][scol] = make_uint2(sk.x, sk.y);
      *(uint2*)&Kl[nxt][srow][scol + 4] = make_uint2(sk.z, sk.w);
      *(uint2*)&Vl[nxt][srow][scol] = make_uint2(sv.x, sv.y);
      *(uint2*)&Vl[nxt][srow][scol + 4] = make_uint2(sv.z, sv.w);
    }

    // ---- l-MFMA + PV ----
    __builtin_amdgcn_s_setprio(1);
    la[0] = __builtin_amdgcn_mfma_f32_16x16x32_bf16(ones, pb0[0], la[0], 0, 0, 0);
    la[0] = __builtin_amdgcn_mfma_f32_16x16x32_bf16(ones, pb0[1], la[0], 0, 0, 0);
    la[1] = __builtin_amdgcn_mfma_f32_16x16x32_bf16(ones, pb1[0], la[1], 0, 0, 0);
    la[1] = __builtin_amdgcn_mfma_f32_16x16x32_bf16(ones, pb1[1], la[1], 0, 0, 0);
#pragma unroll
    for (int dt = 0; dt < 4; ++dt) {
      const bf16_t* vp0 = &Vl[cur][dt * 16 + qi][g4];
#pragma unroll
      for (int kc = 0; kc < 2; ++kc) {
        const bf16_t* vp = vp0 + kc * 32;
        const bf16x8 va = pack8(*(const bf16x4*)vp, *(const bf16x4*)(vp + 16));
        o[0][dt] = __builtin_amdgcn_mfma_f32_16x16x32_bf16(va, pb0[kc], o[0][dt], 0, 0, 0);
        o[1][dt] = __builtin_amdgcn_mfma_f32_16x16x32_bf16(va, pb1[kc], o[1][dt], 0, 0, 0);
      }
    }
    __builtin_amdgcn_s_setprio(0);

    if (t + 1 < nt) __syncthreads();
  };

  for (int t = 0; t < nt; ++t) {
    if ((t & 1) == 0) step(t, kr1, vr1, kr0, vr0);  // even t: staged=set1, prefetch->set0
    else              step(t, kr0, vr0, kr1, vr1);  // odd  t: staged=set0, prefetch->set1
  }

  // ---- epilogue: every lane already holds l for its q in la[g][0] ----
#pragma unroll
  for (int g = 0; g < 2; ++g) {
    const float inv = 1.0f / la[g][0];
    float* op = out + bhoff + (size_t)(qrow0 + g * 16) * D_;
#pragma unroll
    for (int dt = 0; dt < 4; ++dt) {
      float4 w;
      w.x = o[g][dt][0] * inv;
      w.y = o[g][dt][1] * inv;
      w.z = o[g][dt][2] * inv;
      w.w = o[g][dt][3] * inv;
      *(float4*)(op + dt * 16 + g4) = w;
    }
  }
}

extern "C" void kernel_launch(void* const* d_in, const int* in_sizes, int n_in,
                              void* d_out, int out_size, void* d_ws, size_t ws_size,
                              hipStream_t stream) {
  const float* Q = (const float*)d_in[0];
  const float* K = (const float*)d_in[1];
  const float* V = (const float*)d_in[2];
  const unsigned char* mraw = (const unsigned char*)d_in[3];
  float* out = (float*)d_out;

  char* ws = (char*)d_ws;
  bf16_t* Kc = (bf16_t*)(ws + KC_OFF);
  bf16_t* Vtc = (bf16_t*)(ws + VT_OFF);
  int* cidx = (int*)(ws + CIDX_OFF);
  int* nkarr = (int*)(ws + NK_OFF);

  scan_kernel<<<B_, 256, 0, stream>>>(mraw, cidx, nkarr);
  gather_kernel<<<BH_ * 32, 256, 0, stream>>>(K, V, cidx, nkarr, Kc, Vtc);
  attn_main_kernel<<<512, 512, 0, stream>>>(Q, Kc, Vtc, nkarr, out);
}

// Round 10
// 79.161 us; speedup vs baseline: 1.3514x; 1.3514x over previous
//
#include <hip/hip_runtime.h>
#include <hip/hip_bf16.h>

#define B_ 4
#define H_ 16
#define S_ 2048
#define D_ 64
#define BH_ (B_ * H_)
#define VSTR 2048  // compacted key stride (max padded length)

// log2-domain constant: Q pre-scale = 0.125 * log2(e)
#define QS 0.18033688011112042f

typedef __bf16 bf16_t;
typedef __attribute__((ext_vector_type(8))) bf16_t bf16x8;
typedef __attribute__((ext_vector_type(4))) bf16_t bf16x4;
typedef __attribute__((ext_vector_type(4))) float f32x4;

#if __has_builtin(__builtin_amdgcn_exp2f)
#define EX2(x) __builtin_amdgcn_exp2f(x)
#else
#define EX2(x) exp2f(x)
#endif

// ---- workspace layout (bytes) ----
#define KC_OFF 0u          // Kc  [bh][VSTR][64] bf16 = 16.8 MB
#define VT_OFF 16777216u   // Vtc [bh][64][VSTR] bf16 = 16.8 MB
#define CIDX_OFF 33554432u // cidx [B][2048] int
#define NK_OFF 33619968u   // nk [B] int

__device__ __forceinline__ bf16x4 cvt4(const float4 a) {
  return (bf16x4){(bf16_t)a.x, (bf16_t)a.y, (bf16_t)a.z, (bf16_t)a.w};
}

// ======================= scan: mask -> compact key indices =======================
__global__ __launch_bounds__(256) void scan_kernel(const unsigned char* __restrict__ raw,
                                                   int* __restrict__ cidx,
                                                   int* __restrict__ nkarr) {
  const int b = blockIdx.x;
  const int tid = threadIdx.x;
  __shared__ int isBool;
  if (tid == 0) isBool = 0;
  __syncthreads();
  int any = 0;
  for (int i = tid; i < B_ * S_; i += 256)
    if ((i & 3) && raw[i]) any = 1;
  if (any) isBool = 1;  // benign race
  __syncthreads();
  const bool ib = (isBool != 0);

  int flags[8], cnt = 0;
  const int base = tid * 8;
#pragma unroll
  for (int j = 0; j < 8; ++j) {
    const int key = base + j;
    const int m = ib ? (raw[b * S_ + key] ? 1 : 0)
                     : (((const int*)raw)[b * S_ + key] ? 1 : 0);
    flags[j] = m ? 0 : 1;  // keep unmasked
    cnt += flags[j];
  }
  __shared__ int sc[256];
  sc[tid] = cnt;
  __syncthreads();
  for (int off = 1; off < 256; off <<= 1) {  // Hillis-Steele inclusive scan
    const int v = sc[tid];
    const int u = (tid >= off) ? sc[tid - off] : 0;
    __syncthreads();
    sc[tid] = v + u;
    __syncthreads();
  }
  int pos = (tid > 0) ? sc[tid - 1] : 0;  // exclusive
  const int total = sc[255];
  int* cb = cidx + b * VSTR;
#pragma unroll
  for (int j = 0; j < 8; ++j)
    if (flags[j]) cb[pos++] = base + j;
  if (tid == 0) nkarr[b] = total;
  const int padend = ((total + 63) >> 6) << 6;
  for (int i = total + tid; i < padend; i += 256) cb[i] = 0;  // pad -> key 0 (p gated to 0)
}

// ======================= gather: compact K (bf16) + V^T (bf16) =======================
__global__ __launch_bounds__(256) void gather_kernel(const float* __restrict__ K,
                                                     const float* __restrict__ V,
                                                     const int* __restrict__ cidx,
                                                     const int* __restrict__ nkarr,
                                                     bf16_t* __restrict__ Kc,
                                                     bf16_t* __restrict__ Vtc) {
  const int blk = blockIdx.x;  // bh*32 + tile
  const int bh = blk >> 5, tile = blk & 31;
  const int b = bh >> 4;
  if (tile * 64 >= nkarr[b]) return;
  const int tid = threadIdx.x;
  __shared__ int idx[64];
  __shared__ float T[64][65];
  if (tid < 64) idx[tid] = cidx[b * VSTR + tile * 64 + tid];
  __syncthreads();
  {
    const int row = tid >> 2, d0 = (tid & 3) << 4;
    const float* src = K + (size_t)bh * S_ * D_ + (size_t)idx[row] * D_ + d0;
    bf16_t* dst = Kc + (size_t)bh * VSTR * D_ + (size_t)(tile * 64 + row) * D_ + d0;
    const float4 a = ((const float4*)src)[0], bb = ((const float4*)src)[1];
    const float4 c = ((const float4*)src)[2], d = ((const float4*)src)[3];
    *(bf16x4*)(dst) = cvt4(a);
    *(bf16x4*)(dst + 4) = cvt4(bb);
    *(bf16x4*)(dst + 8) = cvt4(c);
    *(bf16x4*)(dst + 12) = cvt4(d);
  }
  const float* vsrc = V + (size_t)bh * S_ * D_;
#pragma unroll
  for (int rep = 0; rep < 4; ++rep) {
    const int i2 = rep * 256 + tid;
    const int row = i2 >> 4, d4 = (i2 & 15) << 2;
    const float4 v = *(const float4*)(vsrc + (size_t)idx[row] * D_ + d4);
    T[row][d4] = v.x; T[row][d4 + 1] = v.y; T[row][d4 + 2] = v.z; T[row][d4 + 3] = v.w;
  }
  __syncthreads();
  bf16_t* vdst = Vtc + (size_t)bh * D_ * VSTR + tile * 64;
#pragma unroll
  for (int rep = 0; rep < 4; ++rep) {
    const int i2 = rep * 256 + tid;
    const int d = i2 >> 4, k4 = (i2 & 15) << 2;
    const bf16x4 o = {(bf16_t)T[k4][d], (bf16_t)T[k4 + 1][d], (bf16_t)T[k4 + 2][d],
                      (bf16_t)T[k4 + 3][d]};
    *(bf16x4*)(vdst + (size_t)d * VSTR + k4) = o;
  }
}

// ======================= main flash kernel =======================
// R8 skeleton (proven 55.8us) + (1) 2-deep prefetch as a MACRO with named
// uint4 ping-pong regs (R9's by-reference lambda forced scratch: WRITE_SIZE
// 35->239MB); (2) l via ones-A MFMA (no ts adds, no epilogue shuffles).
// launch_bounds (512,2): (512,4) empirically caps VGPR at 64 (R8/R9).

__device__ __forceinline__ bf16x8 pack8(const bf16x4 lo, const bf16x4 hi) {
  bf16x8 r;
  r[0] = lo[0]; r[1] = lo[1]; r[2] = lo[2]; r[3] = lo[3];
  r[4] = hi[0]; r[5] = hi[1]; r[6] = hi[2]; r[7] = hi[3];
  return r;
}

__device__ __forceinline__ bf16x8 qpack(const float4 a, const float4 b) {
  bf16x8 r;
  r[0] = (bf16_t)(a.x * QS); r[1] = (bf16_t)(a.y * QS);
  r[2] = (bf16_t)(a.z * QS); r[3] = (bf16_t)(a.w * QS);
  r[4] = (bf16_t)(b.x * QS); r[5] = (bf16_t)(b.y * QS);
  r[6] = (bf16_t)(b.z * QS); r[7] = (bf16_t)(b.w * QS);
  return r;
}

#define STEP(T, SK, SV, PK, PV)                                                    \
  {                                                                                \
    const int cur_ = (T) & 1, nxt_ = cur_ ^ 1;                                     \
    const bool more_ = ((T) + 1 < nt);                                             \
    const int rem_ = nk - (T) * 64;                                                \
    if ((T) + 2 < nt) {                                                            \
      PK = *(const uint4*)(Kgs + (size_t)((T) + 2) * 64 * D_);                     \
      PV = *(const uint4*)(Vgs + ((T) + 2) * 64);                                  \
    }                                                                              \
    bf16x8 pb0_[2], pb1_[2];                                                       \
    __builtin_amdgcn_s_setprio(1);                                                 \
    _Pragma("unroll") for (int kt = 0; kt < 4; ++kt) {                             \
      f32x4 a0 = {0.f, 0.f, 0.f, 0.f}, a1 = a0;                                    \
      _Pragma("unroll") for (int c = 0; c < 2; ++c) {                              \
        const bf16_t* kp = &Kl[cur_][kt * 16 + qi][c * 32 + g4];                   \
        const bf16x8 ka = pack8(*(const bf16x4*)kp, *(const bf16x4*)(kp + 16));    \
        a0 = __builtin_amdgcn_mfma_f32_16x16x32_bf16(ka, qb[0][c], a0, 0, 0, 0);   \
        a1 = __builtin_amdgcn_mfma_f32_16x16x32_bf16(ka, qb[1][c], a1, 0, 0, 0);   \
      }                                                                            \
      if (more_) {                                                                 \
        _Pragma("unroll") for (int r = 0; r < 4; ++r) {                            \
          pb0_[kt >> 1][(kt & 1) * 4 + r] = (bf16_t)EX2(a0[r]);                    \
          pb1_[kt >> 1][(kt & 1) * 4 + r] = (bf16_t)EX2(a1[r]);                    \
        }                                                                          \
      } else {                                                                     \
        _Pragma("unroll") for (int r = 0; r < 4; ++r) {                            \
          const int kidx = kt * 16 + g4 + r;                                       \
          float p0 = EX2(a0[r]);                                                   \
          float p1 = EX2(a1[r]);                                                   \
          p0 = (kidx < rem_) ? p0 : 0.f;                                           \
          p1 = (kidx < rem_) ? p1 : 0.f;                                           \
          pb0_[kt >> 1][(kt & 1) * 4 + r] = (bf16_t)p0;                            \
          pb1_[kt >> 1][(kt & 1) * 4 + r] = (bf16_t)p1;                            \
        }                                                                          \
      }                                                                            \
    }                                                                              \
    __builtin_amdgcn_s_setprio(0);                                                 \
    if (more_) {                                                                   \
      *(uint2*)&Kl[nxt_][srow][scol] = make_uint2(SK.x, SK.y);                     \
      *(uint2*)&Kl[nxt_][srow][scol + 4] = make_uint2(SK.z, SK.w);                 \
    }                                                                              \
    __builtin_amdgcn_s_setprio(1);                                                 \
    la0 = __builtin_amdgcn_mfma_f32_16x16x32_bf16(ones, pb0_[0], la0, 0, 0, 0);    \
    la0 = __builtin_amdgcn_mfma_f32_16x16x32_bf16(ones, pb0_[1], la0, 0, 0, 0);    \
    la1 = __builtin_amdgcn_mfma_f32_16x16x32_bf16(ones, pb1_[0], la1, 0, 0, 0);    \
    la1 = __builtin_amdgcn_mfma_f32_16x16x32_bf16(ones, pb1_[1], la1, 0, 0, 0);    \
    _Pragma("unroll") for (int dt = 0; dt < 4; ++dt) {                             \
      const bf16_t* vp0 = &Vl[cur_][dt * 16 + qi][g4];                             \
      _Pragma("unroll") for (int kc = 0; kc < 2; ++kc) {                           \
        const bf16_t* vp = vp0 + kc * 32;                                          \
        const bf16x8 va = pack8(*(const bf16x4*)vp, *(const bf16x4*)(vp + 16));    \
        o[0][dt] = __builtin_amdgcn_mfma_f32_16x16x32_bf16(va, pb0_[kc], o[0][dt], 0, 0, 0); \
        o[1][dt] = __builtin_amdgcn_mfma_f32_16x16x32_bf16(va, pb1_[kc], o[1][dt], 0, 0, 0); \
      }                                                                            \
    }                                                                              \
    __builtin_amdgcn_s_setprio(0);                                                 \
    if (more_) {                                                                   \
      *(uint2*)&Vl[nxt_][srow][scol] = make_uint2(SV.x, SV.y);                     \
      *(uint2*)&Vl[nxt_][srow][scol + 4] = make_uint2(SV.z, SV.w);                 \
      __syncthreads();                                                             \
    }                                                                              \
  }

__global__ __launch_bounds__(512, 2) void attn_main_kernel(const float* __restrict__ Q,
                                                           const bf16_t* __restrict__ Kc,
                                                           const bf16_t* __restrict__ Vtc,
                                                           const int* __restrict__ nkarr,
                                                           float* __restrict__ out) {
  __shared__ bf16_t Kl[2][64][68];  // 136B rows: conflict-free (measured R1/R3/R7/R8)
  __shared__ bf16_t Vl[2][64][68];

  const int bid = blockIdx.x;
  const int wu = (bid & 7) * 64 + (bid >> 3);  // XCD swizzle, 512 = 8*64 bijective
  const int qt = wu & 7, bh = wu >> 3, b = bh >> 4;

  const int nk = nkarr[b];
  const int nt = (nk + 63) >> 6;

  const int tid = threadIdx.x, wid = tid >> 6, lane = tid & 63;
  const int g4 = ((lane >> 4) & 3) << 2, qi = lane & 15;

  const size_t bhoff = (size_t)bh * (S_ * D_);
  const bf16_t* Kg = Kc + (size_t)bh * VSTR * D_;
  const bf16_t* Vg = Vtc + (size_t)bh * D_ * VSTR;

  // 2 Q fragments (groups of 16 q), fp32 -> scaled bf16, held all kernel
  const int qrow0 = qt * 256 + wid * 32 + qi;
  bf16x8 qb[2][2];
#pragma unroll
  for (int g = 0; g < 2; ++g) {
    const float* qp = Q + bhoff + (size_t)(qrow0 + g * 16) * D_;
#pragma unroll
    for (int c = 0; c < 2; ++c)
      qb[g][c] = qpack(*(const float4*)(qp + c * 32 + g4),
                       *(const float4*)(qp + c * 32 + 16 + g4));
  }

  // all-ones A fragment: C[m][q] = sum_k P[k][q] in every row -> per-lane l
  bf16x8 ones;
#pragma unroll
  for (int j = 0; j < 8; ++j) ones[j] = (bf16_t)1.0f;

  // staging geometry: one row per thread (512 thr x 16B = one 64x64 bf16 tile)
  const int srow = tid >> 3;
  const int scol = (tid & 7) << 3;
  const bf16_t* Kgs = Kg + (size_t)srow * D_ + scol;   // + t*64*D_ per tile
  const bf16_t* Vgs = Vg + (size_t)srow * VSTR + scol; // + t*64  per tile

  // prologue: tile 0 -> LDS[0]; tile 1 -> regs kr1/vr1
  {
    const uint4 k0 = *(const uint4*)(Kgs);
    const uint4 v0 = *(const uint4*)(Vgs);
    *(uint2*)&Kl[0][srow][scol] = make_uint2(k0.x, k0.y);
    *(uint2*)&Kl[0][srow][scol + 4] = make_uint2(k0.z, k0.w);
    *(uint2*)&Vl[0][srow][scol] = make_uint2(v0.x, v0.y);
    *(uint2*)&Vl[0][srow][scol + 4] = make_uint2(v0.z, v0.w);
  }
  uint4 kr0, vr0, kr1, vr1;
  if (nt > 1) {
    kr1 = *(const uint4*)(Kgs + (size_t)64 * D_);
    vr1 = *(const uint4*)(Vgs + 64);
  }
  __syncthreads();

  f32x4 o[2][4];
#pragma unroll
  for (int g = 0; g < 2; ++g)
#pragma unroll
    for (int dt = 0; dt < 4; ++dt) o[g][dt] = (f32x4){0.f, 0.f, 0.f, 0.f};
  f32x4 la0 = {0.f, 0.f, 0.f, 0.f}, la1 = la0;

  int t = 0;
  for (; t + 1 < nt; t += 2) {
    STEP(t, kr1, vr1, kr0, vr0);      // even t: staged = set1, prefetch -> set0
    STEP(t + 1, kr0, vr0, kr1, vr1);  // odd  t: staged = set0, prefetch -> set1
  }
  if (t < nt) STEP(t, kr1, vr1, kr0, vr0);  // tail (odd nt)

  // ---- epilogue: every lane holds l for its q in la*[0] ----
#pragma unroll
  for (int g = 0; g < 2; ++g) {
    const float inv = 1.0f / (g ? la1[0] : la0[0]);
    float* op = out + bhoff + (size_t)(qrow0 + g * 16) * D_;
#pragma unroll
    for (int dt = 0; dt < 4; ++dt) {
      float4 w;
      w.x = o[g][dt][0] * inv;
      w.y = o[g][dt][1] * inv;
      w.z = o[g][dt][2] * inv;
      w.w = o[g][dt][3] * inv;
      *(float4*)(op + dt * 16 + g4) = w;
    }
  }
}

extern "C" void kernel_launch(void* const* d_in, const int* in_sizes, int n_in,
                              void* d_out, int out_size, void* d_ws, size_t ws_size,
                              hipStream_t stream) {
  const float* Q = (const float*)d_in[0];
  const float* K = (const float*)d_in[1];
  const float* V = (const float*)d_in[2];
  const unsigned char* mraw = (const unsigned char*)d_in[3];
  float* out = (float*)d_out;

  char* ws = (char*)d_ws;
  bf16_t* Kc = (bf16_t*)(ws + KC_OFF);
  bf16_t* Vtc = (bf16_t*)(ws + VT_OFF);
  int* cidx = (int*)(ws + CIDX_OFF);
  int* nkarr = (int*)(ws + NK_OFF);

  scan_kernel<<<B_, 256, 0, stream>>>(mraw, cidx, nkarr);
  gather_kernel<<<BH_ * 32, 256, 0, stream>>>(K, V, cidx, nkarr, Kc, Vtc);
  attn_main_kernel<<<512, 512, 0, stream>>>(Q, Kc, Vtc, nkarr, out);
}

// Round 11
// 71.552 us; speedup vs baseline: 1.4952x; 1.1063x over previous
//
#include <hip/hip_runtime.h>
#include <hip/hip_bf16.h>

#define B_ 4
#define H_ 16
#define S_ 2048
#define D_ 64
#define BH_ (B_ * H_)
#define VSTR 2048  // compacted key stride (max padded length)

// log2-domain constant: Q pre-scale = 0.125 * log2(e)
#define QS 0.18033688011112042f

typedef __bf16 bf16_t;
typedef __attribute__((ext_vector_type(8))) bf16_t bf16x8;
typedef __attribute__((ext_vector_type(4))) bf16_t bf16x4;
typedef __attribute__((ext_vector_type(4))) float f32x4;

#if __has_builtin(__builtin_amdgcn_exp2f)
#define EX2(x) __builtin_amdgcn_exp2f(x)
#else
#define EX2(x) exp2f(x)
#endif

// ---- workspace layout (bytes) ----
#define KC_OFF 0u          // Kc  [bh][VSTR][64] bf16 (d chunk-permuted) = 16.8 MB
#define VT_OFF 16777216u   // Vtc [bh][64][VSTR] bf16 (key chunk-permuted per 64-tile) = 16.8 MB
#define CIDX_OFF 33554432u // cidx [B][2048] int
#define NK_OFF 33619968u   // nk [B] int

__device__ __forceinline__ bf16x4 cvt4(const float4 a) {
  return (bf16x4){(bf16_t)a.x, (bf16_t)a.y, (bf16_t)a.z, (bf16_t)a.w};
}

// ======================= scan: mask -> compact key indices =======================
__global__ __launch_bounds__(256) void scan_kernel(const unsigned char* __restrict__ raw,
                                                   int* __restrict__ cidx,
                                                   int* __restrict__ nkarr) {
  const int b = blockIdx.x;
  const int tid = threadIdx.x;
  __shared__ int isBool;
  if (tid == 0) isBool = 0;
  __syncthreads();
  int any = 0;
  for (int i = tid; i < B_ * S_; i += 256)
    if ((i & 3) && raw[i]) any = 1;
  if (any) isBool = 1;  // benign race
  __syncthreads();
  const bool ib = (isBool != 0);

  int flags[8], cnt = 0;
  const int base = tid * 8;
#pragma unroll
  for (int j = 0; j < 8; ++j) {
    const int key = base + j;
    const int m = ib ? (raw[b * S_ + key] ? 1 : 0)
                     : (((const int*)raw)[b * S_ + key] ? 1 : 0);
    flags[j] = m ? 0 : 1;  // keep unmasked
    cnt += flags[j];
  }
  __shared__ int sc[256];
  sc[tid] = cnt;
  __syncthreads();
  for (int off = 1; off < 256; off <<= 1) {  // Hillis-Steele inclusive scan
    const int v = sc[tid];
    const int u = (tid >= off) ? sc[tid - off] : 0;
    __syncthreads();
    sc[tid] = v + u;
    __syncthreads();
  }
  int pos = (tid > 0) ? sc[tid - 1] : 0;  // exclusive
  const int total = sc[255];
  int* cb = cidx + b * VSTR;
#pragma unroll
  for (int j = 0; j < 8; ++j)
    if (flags[j]) cb[pos++] = base + j;
  if (tid == 0) nkarr[b] = total;
  const int padend = ((total + 63) >> 6) << 6;
  for (int i = total + tid; i < padend; i += 256) cb[i] = 0;  // pad -> key 0 (p gated to 0)
}

// ======================= gather: compact K + V^T, fragment-chunked =======================
// Chunk cc = c*4+g (cc 0..7) holds elems {c*32+g*4+0..3, c*32+16+g*4+0..3} of
// the 64-wide dim (d for Kc, key-within-tile for Vtc) -> one MFMA fragment is
// a contiguous 16B chunk, enabling ds_read_b128 in the main kernel.
__global__ __launch_bounds__(256) void gather_kernel(const float* __restrict__ K,
                                                     const float* __restrict__ V,
                                                     const int* __restrict__ cidx,
                                                     const int* __restrict__ nkarr,
                                                     bf16_t* __restrict__ Kc,
                                                     bf16_t* __restrict__ Vtc) {
  const int blk = blockIdx.x;  // bh*32 + tile
  const int bh = blk >> 5, tile = blk & 31;
  const int b = bh >> 4;
  if (tile * 64 >= nkarr[b]) return;
  const int tid = threadIdx.x;
  __shared__ int idx[64];
  __shared__ float T[64][65];
  if (tid < 64) idx[tid] = cidx[b * VSTR + tile * 64 + tid];
  __syncthreads();
  // K gather, d chunk-permuted: thread (row, g) writes chunks g and 4+g.
  {
    const int row = tid >> 2, g = tid & 3;
    const float* src = K + (size_t)bh * S_ * D_ + (size_t)idx[row] * D_;
    bf16_t* dst = Kc + (size_t)bh * VSTR * D_ + (size_t)(tile * 64 + row) * D_;
#pragma unroll
    for (int c = 0; c < 2; ++c) {
      const float4 lo = *(const float4*)(src + c * 32 + g * 4);
      const float4 hi = *(const float4*)(src + c * 32 + 16 + g * 4);
      *(bf16x4*)(dst + (c * 4 + g) * 8) = cvt4(lo);
      *(bf16x4*)(dst + (c * 4 + g) * 8 + 4) = cvt4(hi);
    }
  }
  // V gather + 64x64 transpose via LDS
  const float* vsrc = V + (size_t)bh * S_ * D_;
#pragma unroll
  for (int rep = 0; rep < 4; ++rep) {
    const int i2 = rep * 256 + tid;
    const int row = i2 >> 4, d4 = (i2 & 15) << 2;
    const float4 v = *(const float4*)(vsrc + (size_t)idx[row] * D_ + d4);
    T[row][d4] = v.x; T[row][d4 + 1] = v.y; T[row][d4 + 2] = v.z; T[row][d4 + 3] = v.w;
  }
  __syncthreads();
  // write V^T with key chunk-permutation within the 64-key tile
  bf16_t* vdst = Vtc + (size_t)bh * D_ * VSTR + tile * 64;
#pragma unroll
  for (int rep = 0; rep < 4; ++rep) {
    const int i2 = rep * 256 + tid;
    const int d = i2 >> 4, k4 = (i2 & 15) << 2;  // logical keys k4..k4+3
    const int kc = k4 >> 5, within = k4 & 31;
    const int g = (within & 15) >> 2, half = (within & 16) ? 4 : 0;
    const int pos = (kc * 4 + g) * 8 + half;      // physical slot (contiguous x4)
    const bf16x4 o = {(bf16_t)T[k4][d], (bf16_t)T[k4 + 1][d], (bf16_t)T[k4 + 2][d],
                      (bf16_t)T[k4 + 3][d]};
    *(bf16x4*)(vdst + (size_t)d * VSTR + pos) = o;
  }
}

// ======================= main flash kernel =======================
// R8 skeleton (proven 55.8us: 8 waves x 32q, grid 512, 1-deep staging,
// 1 barrier/tile) with fragment-chunked b128 LDS: every frag read is ONE
// ds_read_b128, every staging write ONE ds_write_b128 (36 -> 18 DS ops per
// wave-tile; DS pipe was the largest issue cost ~33us/CU). Unpadded 128B rows
// + XOR chunk swizzle (chunk ^ (row&7)) -> 2-way bank aliasing (free, m136),
// applied symmetrically at write and read (global stays linear-chunked).

__device__ __forceinline__ bf16x8 qpack(const float4 a, const float4 b) {
  bf16x8 r;
  r[0] = (bf16_t)(a.x * QS); r[1] = (bf16_t)(a.y * QS);
  r[2] = (bf16_t)(a.z * QS); r[3] = (bf16_t)(a.w * QS);
  r[4] = (bf16_t)(b.x * QS); r[5] = (bf16_t)(b.y * QS);
  r[6] = (bf16_t)(b.z * QS); r[7] = (bf16_t)(b.w * QS);
  return r;
}

__global__ __launch_bounds__(512, 4) void attn_main_kernel(const float* __restrict__ Q,
                                                           const bf16_t* __restrict__ Kc,
                                                           const bf16_t* __restrict__ Vtc,
                                                           const int* __restrict__ nkarr,
                                                           float* __restrict__ out) {
  __shared__ bf16_t Kl[2][64][64];  // 128B rows, chunk-swizzled; 16KB
  __shared__ bf16_t Vl[2][64][64];  // 16KB

  const int bid = blockIdx.x;
  const int wu = (bid & 7) * 64 + (bid >> 3);  // XCD swizzle, 512 = 8*64 bijective
  const int qt = wu & 7, bh = wu >> 3, b = bh >> 4;

  const int nk = nkarr[b];
  const int nt = (nk + 63) >> 6;

  const int tid = threadIdx.x, wid = tid >> 6, lane = tid & 63;
  const int gg = (lane >> 4) & 3, g4 = gg << 2, qi = lane & 15;
  const int q7 = qi & 7;
  const int koff0 = ((gg) ^ q7) << 3;      // c=0 frag: swizzled elem offset
  const int koff1 = ((4 + gg) ^ q7) << 3;  // c=1 frag

  const size_t bhoff = (size_t)bh * (S_ * D_);
  const bf16_t* Kg = Kc + (size_t)bh * VSTR * D_;
  const bf16_t* Vg = Vtc + (size_t)bh * D_ * VSTR;

  // 2 Q fragments (groups of 16 q), fp32 -> scaled bf16, held all kernel.
  // (Q global is NOT permuted; qpack builds the frag's d-order directly.)
  const int qrow0 = qt * 256 + wid * 32 + qi;
  bf16x8 qb[2][2];
#pragma unroll
  for (int g = 0; g < 2; ++g) {
    const float* qp = Q + bhoff + (size_t)(qrow0 + g * 16) * D_;
#pragma unroll
    for (int c = 0; c < 2; ++c)
      qb[g][c] = qpack(*(const float4*)(qp + c * 32 + g4),
                       *(const float4*)(qp + c * 32 + 16 + g4));
  }

  // staging: thread (srow, scc) copies global chunk scc of row srow to
  // swizzled LDS slot (scc ^ (srow&7)). 512 thr x 16B = one 64x64 tile.
  const int srow = tid >> 3;
  const int scc = tid & 7;
  const int soff = ((scc ^ (srow & 7)) << 3);
  const bf16_t* Kgs = Kg + (size_t)srow * D_ + scc * 8;   // + t*64*D_ per tile
  const bf16_t* Vgs = Vg + (size_t)srow * VSTR + scc * 8; // + t*64  per tile

  // prologue: stage tile 0 -> buf 0
  {
    const uint4 k0 = *(const uint4*)Kgs;
    const uint4 v0 = *(const uint4*)Vgs;
    *(uint4*)&Kl[0][srow][soff] = k0;
    *(uint4*)&Vl[0][srow][soff] = v0;
  }
  __syncthreads();

  f32x4 o[2][4];
#pragma unroll
  for (int g = 0; g < 2; ++g)
#pragma unroll
    for (int dt = 0; dt < 4; ++dt) o[g][dt] = (f32x4){0.f, 0.f, 0.f, 0.f};
  float lrun0 = 0.f, lrun1 = 0.f;

  for (int t = 0; t < nt; ++t) {
    const int cur = t & 1;
    const int nxt = cur ^ 1;
    const bool more = (t + 1 < nt);
    const int kv = (t + 1) * 64;
    const int rem = nk - t * 64;  // < 64 only on the last tile

    // ---- issue next-tile global loads (consumed after PV) ----
    uint4 k0, v0;
    if (more) {
      k0 = *(const uint4*)(Kgs + (size_t)kv * D_);
      v0 = *(const uint4*)(Vgs + kv);
    }

    // ---- QK^T with fused exp2 softmax (log2 domain, no max; scores bounded) ----
    bf16x8 pb0[2], pb1[2];
    float ts0 = 0.f, ts1 = 0.f;
    __builtin_amdgcn_s_setprio(1);
#pragma unroll
    for (int kt = 0; kt < 4; ++kt) {
      const bf16_t* krow = &Kl[cur][kt * 16 + qi][0];
      f32x4 a0 = {0.f, 0.f, 0.f, 0.f}, a1 = a0;
      {
        const bf16x8 ka = *(const bf16x8*)(krow + koff0);
        a0 = __builtin_amdgcn_mfma_f32_16x16x32_bf16(ka, qb[0][0], a0, 0, 0, 0);
        a1 = __builtin_amdgcn_mfma_f32_16x16x32_bf16(ka, qb[1][0], a1, 0, 0, 0);
      }
      {
        const bf16x8 ka = *(const bf16x8*)(krow + koff1);
        a0 = __builtin_amdgcn_mfma_f32_16x16x32_bf16(ka, qb[0][1], a0, 0, 0, 0);
        a1 = __builtin_amdgcn_mfma_f32_16x16x32_bf16(ka, qb[1][1], a1, 0, 0, 0);
      }
      if (more) {  // full tile: ungated exp2
#pragma unroll
        for (int r = 0; r < 4; ++r) {
          const float p0 = EX2(a0[r]);
          const float p1 = EX2(a1[r]);
          ts0 += p0; ts1 += p1;
          pb0[kt >> 1][(kt & 1) * 4 + r] = (bf16_t)p0;
          pb1[kt >> 1][(kt & 1) * 4 + r] = (bf16_t)p1;
        }
      } else {  // tail tile: gate pad slots (logical key >= nk)
#pragma unroll
        for (int r = 0; r < 4; ++r) {
          const int kidx = kt * 16 + g4 + r;
          float p0 = EX2(a0[r]);
          float p1 = EX2(a1[r]);
          p0 = (kidx < rem) ? p0 : 0.f;
          p1 = (kidx < rem) ? p1 : 0.f;
          ts0 += p0; ts1 += p1;
          pb0[kt >> 1][(kt & 1) * 4 + r] = (bf16_t)p0;
          pb1[kt >> 1][(kt & 1) * 4 + r] = (bf16_t)p1;
        }
      }
    }
    __builtin_amdgcn_s_setprio(0);
    lrun0 += ts0;
    lrun1 += ts1;

    // ---- write staged K (single b128; dies early; nxt safe post-barrier) ----
    if (more) *(uint4*)&Kl[nxt][srow][soff] = k0;

    // ---- PV: O^T[d][q] += V^T[d][key] * P^T[key][q] ----
    __builtin_amdgcn_s_setprio(1);
#pragma unroll
    for (int dt = 0; dt < 4; ++dt) {
      const bf16_t* vrow = &Vl[cur][dt * 16 + qi][0];
      {
        const bf16x8 va = *(const bf16x8*)(vrow + koff0);  // kc=0 frag
        o[0][dt] = __builtin_amdgcn_mfma_f32_16x16x32_bf16(va, pb0[0], o[0][dt], 0, 0, 0);
        o[1][dt] = __builtin_amdgcn_mfma_f32_16x16x32_bf16(va, pb1[0], o[1][dt], 0, 0, 0);
      }
      {
        const bf16x8 va = *(const bf16x8*)(vrow + koff1);  // kc=1 frag
        o[0][dt] = __builtin_amdgcn_mfma_f32_16x16x32_bf16(va, pb0[1], o[0][dt], 0, 0, 0);
        o[1][dt] = __builtin_amdgcn_mfma_f32_16x16x32_bf16(va, pb1[1], o[1][dt], 0, 0, 0);
      }
    }
    __builtin_amdgcn_s_setprio(0);

    // ---- write staged V (single b128), one barrier/tile ----
    if (more) {
      *(uint4*)&Vl[nxt][srow][soff] = v0;
      __syncthreads();
    }
  }

  // ---- epilogue: row-reduce l, scale, write ----
#pragma unroll
  for (int g = 0; g < 2; ++g) {
    float lr = g ? lrun1 : lrun0;
    lr += __shfl_xor(lr, 16);
    lr += __shfl_xor(lr, 32);
    const float inv = 1.0f / lr;
    float* op = out + bhoff + (size_t)(qrow0 + g * 16) * D_;
#pragma unroll
    for (int dt = 0; dt < 4; ++dt) {
      float4 w;
      w.x = o[g][dt][0] * inv;
      w.y = o[g][dt][1] * inv;
      w.z = o[g][dt][2] * inv;
      w.w = o[g][dt][3] * inv;
      *(float4*)(op + dt * 16 + g4) = w;
    }
  }
}

extern "C" void kernel_launch(void* const* d_in, const int* in_sizes, int n_in,
                              void* d_out, int out_size, void* d_ws, size_t ws_size,
                              hipStream_t stream) {
  const float* Q = (const float*)d_in[0];
  const float* K = (const float*)d_in[1];
  const float* V = (const float*)d_in[2];
  const unsigned char* mraw = (const unsigned char*)d_in[3];
  float* out = (float*)d_out;

  char* ws = (char*)d_ws;
  bf16_t* Kc = (bf16_t*)(ws + KC_OFF);
  bf16_t* Vtc = (bf16_t*)(ws + VT_OFF);
  int* cidx = (int*)(ws + CIDX_OFF);
  int* nkarr = (int*)(ws + NK_OFF);

  scan_kernel<<<B_, 256, 0, stream>>>(mraw, cidx, nkarr);
  gather_kernel<<<BH_ * 32, 256, 0, stream>>>(K, V, cidx, nkarr, Kc, Vtc);
  attn_main_kernel<<<512, 512, 0, stream>>>(Q, Kc, Vtc, nkarr, out);
}